// Round 1
// baseline (3445.214 us; speedup 1.0000x reference)
//
#include <hip/hip_runtime.h>
#include <math.h>

#define FD 64
#define NRBF 20
#define CUT 5.0f
#define EPSV 1e-8f
#define PI_F 3.14159265358979f

__device__ __forceinline__ float wredsum(float v){
#pragma unroll
  for (int m = 32; m >= 1; m >>= 1) v += __shfl_xor(v, m, 64);
  return v;
}
__device__ __forceinline__ float wredmax(float v){
#pragma unroll
  for (int m = 32; m >= 1; m >>= 1) v = fmaxf(v, __shfl_xor(v, m, 64));
  return v;
}
__device__ __forceinline__ float silu_f(float x){ return x * (1.0f / (1.0f + __expf(-x))); }

// ---- K0: per-pair precompute: dir(3), fcut(1), phi*fcut(20) -> 24 floats ----
__global__ __launch_bounds__(256) void k_pairprep(const float* __restrict__ Rij,
                                                  float* __restrict__ pair, int P)
{
  int p = blockIdx.x * blockDim.x + threadIdx.x;
  if (p >= P) return;
  float rx = Rij[3*p+0], ry = Rij[3*p+1], rz = Rij[3*p+2];
  float d = sqrtf(rx*rx + ry*ry + rz*rz);
  float inv = 1.0f / d;
  float fc = (d < CUT) ? 0.5f * (__cosf(PI_F * d / CUT) + 1.0f) : 0.0f;
  float* pr = pair + (size_t)p * 24;
  pr[0] = rx*inv; pr[1] = ry*inv; pr[2] = rz*inv; pr[3] = fc;
  const float width = CUT / (float)(NRBF - 1);
#pragma unroll
  for (int r = 0; r < NRBF; ++r){
    float t = (d - width * (float)r) / width;
    pr[4+r] = __expf(-0.5f * t * t) * fc;
  }
}

// ---- K_init: q = embed[Z] ----
__global__ __launch_bounds__(256) void k_init_q(const int* __restrict__ Z,
                                                const float* __restrict__ embed,
                                                float* __restrict__ q, int Ntot)
{
  int t = blockIdx.x * blockDim.x + threadIdx.x;
  if (t >= Ntot * FD) return;
  int n = t >> 6, f = t & 63;
  q[t] = embed[Z[n]*FD + f];
}

// ---- K1: per-atom: X = silu(q@cW1+cb1)@cW2+cb2 ; CV = compress(mu) ----
// one wave per atom (lane = f), 4 atoms per 256-thread block
__global__ __launch_bounds__(256) void k_atom_pre(
    const float* __restrict__ q, const float* __restrict__ mu,
    const float* __restrict__ cW1, const float* __restrict__ cb1,
    const float* __restrict__ cW2, const float* __restrict__ cb2,
    const float* __restrict__ pW1, const float* __restrict__ pb1,
    const float* __restrict__ pW2, const float* __restrict__ pb2,
    float* __restrict__ X, float* __restrict__ CV, int Ntot)
{
  __shared__ float qs[4][64];
  __shared__ float h1[4][64];
  __shared__ float sbuf[4][128];
  __shared__ float hc[4][32];
  int w = threadIdx.x >> 6;
  int f = threadIdx.x & 63;
  int n = blockIdx.x * 4 + w;
  bool ok = (n < Ntot);
  if (!ok) n = Ntot - 1;

  float qv = q[(size_t)n*64 + f];
  qs[w][f] = qv;
  __syncthreads();

  float acc = cb1[f];
#pragma unroll
  for (int k = 0; k < 64; ++k) acc = fmaf(qs[w][k], cW1[k*64 + f], acc);
  h1[w][f] = silu_f(acc);

  const float* mun = mu + (size_t)n * 384;
  float m0a = mun[0*128 + f],      m1a = mun[1*128 + f],      m2a = mun[2*128 + f];
  float m0b = mun[0*128 + 64 + f], m1b = mun[1*128 + 64 + f], m2b = mun[2*128 + 64 + f];
  sbuf[w][f]      = sqrtf(m0a*m0a + m1a*m1a + m2a*m2a + EPSV);
  sbuf[w][64 + f] = sqrtf(m0b*m0b + m1b*m1b + m2b*m2b + EPSV);
  __syncthreads();   // protects h1 and sbuf

  float x0 = cb2[f], x1 = cb2[64+f], x2 = cb2[128+f];
#pragma unroll
  for (int k = 0; k < 64; ++k){
    float h = h1[w][k];
    x0 = fmaf(h, cW2[k*192 + f],       x0);
    x1 = fmaf(h, cW2[k*192 + 64 + f],  x1);
    x2 = fmaf(h, cW2[k*192 + 128 + f], x2);
  }
  if (ok){
    float* Xn = X + (size_t)n*192;
    Xn[f] = x0; Xn[64+f] = x1; Xn[128+f] = x2;
  }

  // compress hidden: h = relu(s @ pW1 + pb1), k = lane&31 (upper half duplicates)
  int ki = f & 31;
  float ah = pb1[ki];
#pragma unroll
  for (int c = 0; c < 128; ++c) ah = fmaf(sbuf[w][c], pW1[c*32 + ki], ah);
  if (f < 32) hc[w][f] = fmaxf(ah, 0.0f);
  __syncthreads();

  float logit = pb2[f];
#pragma unroll
  for (int k = 0; k < 32; ++k) logit = fmaf(hc[w][k], pW2[k*64 + f], logit);
  float mx = wredmax(logit);
  float e  = __expf(logit - mx);
  float se = wredsum(e);
  float wt = e / se;
  float v0 = wredsum(m0a + m0b);
  float v1 = wredsum(m1a + m1b);
  float v2 = wredsum(m2a + m2b);
  if (ok){
    float* cvn = CV + (size_t)n*192;
    cvn[f] = v0 * wt; cvn[64+f] = v1 * wt; cvn[128+f] = v2 * wt;
  }
}

// ---- K2: per-pair: filters on the fly, gather X[j], CV[j], atomic scatter to i ----
__global__ __launch_bounds__(256) void k_edge(
    const float* __restrict__ pair, const int* __restrict__ idx_i, const int* __restrict__ idx_j,
    const float* __restrict__ fW, const float* __restrict__ fb,
    const float* __restrict__ X, const float* __restrict__ CV,
    float* __restrict__ dq, float* __restrict__ dmu, int l, int P)
{
  int w = threadIdx.x >> 6;
  int f = threadIdx.x & 63;
  int p = blockIdx.x * 4 + w;
  if (p >= P) return;
  const float* pr = pair + (size_t)p * 24;
  float d0 = pr[0], d1 = pr[1], d2 = pr[2], fc = pr[3];
  int i = idx_i[p], j = idx_j[p];
  const int col = l * 192;
  float w0 = fb[col + f] * fc, w1 = fb[col + 64 + f] * fc, w2 = fb[col + 128 + f] * fc;
#pragma unroll
  for (int r = 0; r < NRBF; ++r){
    float ph = pr[4 + r];
    const float* fr = fW + r*384 + col;
    w0 = fmaf(ph, fr[f],       w0);
    w1 = fmaf(ph, fr[64 + f],  w1);
    w2 = fmaf(ph, fr[128 + f], w2);
  }
  const float* Xj = X + (size_t)j * 192;
  float dqv = Xj[f]       * w0;
  float dmR = Xj[64 + f]  * w1;
  float dmm = Xj[128 + f] * w2;
  const float* cvj = CV + (size_t)j * 192;
  atomicAdd(&dq[(size_t)i*64 + f], dqv);
  atomicAdd(&dmu[(size_t)i*192 + f],       fmaf(dmR, d0, dmm * cvj[f]));
  atomicAdd(&dmu[(size_t)i*192 + 64 + f],  fmaf(dmR, d1, dmm * cvj[64 + f]));
  atomicAdd(&dmu[(size_t)i*192 + 128 + f], fmaf(dmR, d2, dmm * cvj[128 + f]));
}

// ---- K3: per-atom: mu_int = dmu+cvi; rec MLP -> sw row; fused dtm/tv; full mixing ----
__global__ __launch_bounds__(256) void k_atom_post(
    float* __restrict__ q, float* __restrict__ mu,
    const float* __restrict__ dq, const float* __restrict__ dmuA, const float* __restrict__ CV,
    const float* __restrict__ rW1, const float* __restrict__ rb1,
    const float* __restrict__ rW2, const float* __restrict__ rb2,
    const float* __restrict__ mW1, const float* __restrict__ mb1,
    const float* __restrict__ mW2, const float* __restrict__ mb2,
    const float* __restrict__ Wm, int Ntot)
{
  __shared__ float mus[4][3][64];
  __shared__ float sv[4][64];
  __shared__ float hr[4][32];
  __shared__ float av[4][128];
  __shared__ float h2s[4][64];
  int w = threadIdx.x >> 6;
  int f = threadIdx.x & 63;
  int n = blockIdx.x * 4 + w;
  bool ok = (n < Ntot);
  if (!ok) n = Ntot - 1;

  float qn = q[(size_t)n*64 + f] + dq[(size_t)n*64 + f];
  const float* dmn = dmuA + (size_t)n*192;
  const float* cvn = CV   + (size_t)n*192;
  float m0 = dmn[f]       + cvn[f];
  float m1 = dmn[64 + f]  + cvn[64 + f];
  float m2 = dmn[128 + f] + cvn[128 + f];
  mus[w][0][f] = m0; mus[w][1][f] = m1; mus[w][2][f] = m2;
  sv[w][f] = sqrtf(m0*m0 + m1*m1 + m2*m2 + EPSV);
  __syncthreads();

  int ki = f & 31;
  float ah = rb1[ki];
#pragma unroll
  for (int c = 0; c < 64; ++c) ah = fmaf(sv[w][c], rW1[c*32 + ki], ah);
  if (f < 32) hr[w][f] = fmaxf(ah, 0.0f);
  __syncthreads();

  // sw[f, 0..63] with 64 register accumulators, k-outer (cache-friendly streaming)
  float swa[64];
  const float4* rb2v = (const float4*)(rb2 + f*64);
#pragma unroll
  for (int c4 = 0; c4 < 16; ++c4){
    float4 b = rb2v[c4];
    swa[c4*4+0] = b.x; swa[c4*4+1] = b.y; swa[c4*4+2] = b.z; swa[c4*4+3] = b.w;
  }
  for (int k = 0; k < 32; ++k){
    float hk = hr[w][k];
    const float4* wrow = (const float4*)(rW2 + (size_t)k*4096 + f*64);
#pragma unroll
    for (int c4 = 0; c4 < 16; ++c4){
      float4 wv = wrow[c4];
      swa[c4*4+0] = fmaf(hk, wv.x, swa[c4*4+0]);
      swa[c4*4+1] = fmaf(hk, wv.y, swa[c4*4+1]);
      swa[c4*4+2] = fmaf(hk, wv.z, swa[c4*4+2]);
      swa[c4*4+3] = fmaf(hk, wv.w, swa[c4*4+3]);
    }
  }
  // tv[d][f] = sum_c mus[d][c] * (sw[f,c] * G[c,f]),  G[c,f] = sum_d mus[d][c]*mus[d][f]
  float tv0 = 0.f, tv1 = 0.f, tv2 = 0.f;
#pragma unroll
  for (int c = 0; c < 64; ++c){
    float a0 = mus[w][0][c], a1 = mus[w][1][c], a2 = mus[w][2][c];
    float Gc = a0*m0 + a1*m1 + a2*m2;
    float mm = swa[c] * Gc;
    tv0 = fmaf(a0, mm, tv0);
    tv1 = fmaf(a1, mm, tv1);
    tv2 = fmaf(a2, mm, tv2);
  }

  // mixing: mu_mix = mu_int @ Wm  ->  mu_V (g=f), mu_W (g=64+f)
  float muV0=0,muV1=0,muV2=0,muW0=0,muW1=0,muW2=0;
#pragma unroll
  for (int k = 0; k < 64; ++k){
    float a0 = mus[w][0][k], a1 = mus[w][1][k], a2 = mus[w][2][k];
    float wv = Wm[k*128 + f];
    float ww = Wm[k*128 + 64 + f];
    muV0 = fmaf(a0, wv, muV0); muV1 = fmaf(a1, wv, muV1); muV2 = fmaf(a2, wv, muV2);
    muW0 = fmaf(a0, ww, muW0); muW1 = fmaf(a1, ww, muW1); muW2 = fmaf(a2, ww, muW2);
  }
  float muVn = sqrtf(muV0*muV0 + muV1*muV1 + muV2*muV2 + EPSV);
  av[w][f] = qn; av[w][64 + f] = muVn;
  __syncthreads();

  float a2acc = mb1[f];
#pragma unroll
  for (int k = 0; k < 128; ++k) a2acc = fmaf(av[w][k], mW1[k*64 + f], a2acc);
  h2s[w][f] = silu_f(a2acc);
  __syncthreads();

  float y0 = mb2[f], y1 = mb2[64+f], y2 = mb2[128+f];
#pragma unroll
  for (int k = 0; k < 64; ++k){
    float h = h2s[w][k];
    y0 = fmaf(h, mW2[k*192 + f],       y0);
    y1 = fmaf(h, mW2[k*192 + 64 + f],  y1);
    y2 = fmaf(h, mW2[k*192 + 128 + f], y2);
  }
  float dot = muV0*muW0 + muV1*muW1 + muV2*muW2;
  if (ok){
    q[(size_t)n*64 + f] = qn + y0 + y2*dot;
    float* mun = mu + (size_t)n*384;
    mun[0*128 + f] = fmaf(y1, muW0, m0); mun[0*128 + 64 + f] = tv0;
    mun[1*128 + f] = fmaf(y1, muW1, m1); mun[1*128 + 64 + f] = tv1;
    mun[2*128 + f] = fmaf(y1, muW2, m2); mun[2*128 + 64 + f] = tv2;
  }
}

extern "C" void kernel_launch(void* const* d_in, const int* in_sizes, int n_in,
                              void* d_out, int out_size, void* d_ws, size_t ws_size,
                              hipStream_t stream)
{
  const int*   Z      = (const int*)  d_in[0];
  const float* Rij    = (const float*)d_in[1];
  const int*   idx_i  = (const int*)  d_in[2];
  const int*   idx_j  = (const int*)  d_in[3];
  const float* embed  = (const float*)d_in[5];
  const float* fW     = (const float*)d_in[6];
  const float* fb     = (const float*)d_in[7];
  const float* ctxW1  = (const float*)d_in[8];
  const float* ctxb1  = (const float*)d_in[9];
  const float* ctxW2  = (const float*)d_in[10];
  const float* ctxb2  = (const float*)d_in[11];
  const float* compW1 = (const float*)d_in[12];
  const float* compb1 = (const float*)d_in[13];
  const float* compW2 = (const float*)d_in[14];
  const float* compb2 = (const float*)d_in[15];
  const float* recW1  = (const float*)d_in[16];
  const float* recb1  = (const float*)d_in[17];
  const float* recW2  = (const float*)d_in[18];
  const float* recb2  = (const float*)d_in[19];
  const float* mixW1  = (const float*)d_in[20];
  const float* mixb1  = (const float*)d_in[21];
  const float* mixW2  = (const float*)d_in[22];
  const float* mixb2  = (const float*)d_in[23];
  const float* muMixW = (const float*)d_in[24];

  const int N = in_sizes[0];
  const int P = in_sizes[1] / 3;

  float* ws   = (float*)d_ws;
  float* pair = ws;                        // P*24
  float* q    = pair + (size_t)P*24;       // N*64
  float* mu   = q    + (size_t)N*64;       // N*384
  float* X    = mu   + (size_t)N*384;      // N*192
  float* CV   = X    + (size_t)N*192;      // N*192
  float* dq   = CV   + (size_t)N*192;      // N*64
  float* dmu  = dq   + (size_t)N*64;       // N*192

  k_pairprep<<<(P + 255)/256, 256, 0, stream>>>(Rij, pair, P);
  hipMemsetAsync(mu, 0, (size_t)N*384*sizeof(float), stream);
  k_init_q<<<(N*FD + 255)/256, 256, 0, stream>>>(Z, embed, q, N);

  const int ablk = (N + 3) / 4;
  const int pblk = (P + 3) / 4;
  for (int l = 0; l < 2; ++l){
    hipMemsetAsync(dq,  0, (size_t)N*64 *sizeof(float), stream);
    hipMemsetAsync(dmu, 0, (size_t)N*192*sizeof(float), stream);
    k_atom_pre<<<ablk, 256, 0, stream>>>(q, mu,
        ctxW1 + (size_t)l*64*64,  ctxb1 + (size_t)l*64,
        ctxW2 + (size_t)l*64*192, ctxb2 + (size_t)l*192,
        compW1 + (size_t)l*128*32, compb1 + (size_t)l*32,
        compW2 + (size_t)l*32*64,  compb2 + (size_t)l*64,
        X, CV, N);
    k_edge<<<pblk, 256, 0, stream>>>(pair, idx_i, idx_j, fW, fb, X, CV, dq, dmu, l, P);
    k_atom_post<<<ablk, 256, 0, stream>>>(q, mu, dq, dmu, CV,
        recW1 + (size_t)l*64*32,  recb1 + (size_t)l*32,
        recW2 + (size_t)l*32*4096, recb2 + (size_t)l*4096,
        mixW1 + (size_t)l*128*64, mixb1 + (size_t)l*64,
        mixW2 + (size_t)l*64*192, mixb2 + (size_t)l*192,
        muMixW + (size_t)l*64*128, N);
  }

  hipMemcpyAsync(d_out, q, (size_t)N*64*sizeof(float), hipMemcpyDeviceToDevice, stream);
  hipMemcpyAsync((float*)d_out + (size_t)N*64, mu, (size_t)N*384*sizeof(float),
                 hipMemcpyDeviceToDevice, stream);
}